// Round 6
// baseline (235.574 us; speedup 1.0000x reference)
//
#include <hip/hip_runtime.h>
#include <hip/hip_bf16.h>

#define HIDN   64
#define NHEADS 8
#define DHEAD  8
#define NLAY   2
#define BB     4
#define SS     12
#define NNODE  512
#define NEDGE  8192
#define XELEMS (BB * SS * NNODE * 3)      // 73728
#define ROWS   (BB * SS * NNODE)          // 24576
#define QSCALE 0.51006967f                // (1/sqrt(8)) * log2(e): exp(x)=exp2(x*log2e)

typedef unsigned short u16;
typedef unsigned int   u32;
typedef __attribute__((ext_vector_type(4))) float f4;   // indexable float4

__device__ __forceinline__ float b2f(u16 u) {
    union { u32 i; float f; } c; c.i = ((u32)u) << 16; return c.f;
}
// decode element i of a raw input tensor (fl=1 -> fp32, fl=0 -> bf16)
__device__ __forceinline__ float ld(const void* p, int i, int fl) {
    return fl ? ((const float*)p)[i] : b2f(((const u16*)p)[i]);
}

// -------- dtype detection FALLBACK (only if in_sizes is ambiguous) -----------
__global__ void detect_kernel(const u16* __restrict__ x, int* __restrict__ flag) {
    int i0 = blockIdx.x * 256 + threadIdx.x;
    int bad = 0;
    for (int i = i0; i < XELEMS; i += 64 * 256) {
        float v = fabsf(b2f(x[i]));
        if (!(v <= 100.f)) bad = 1;   // catches huge AND NaN
    }
    if (bad) atomicOr(flag, 1);       // flag=1 -> inputs are fp32
}

// ---------------- PREP mega-kernel: input_proj + weight pack + mask/CSR ------
// grid = 384 (input_proj, 8 out/thread) + 96 (pack) + 1 (mask+csr), 512 threads.
struct PrepArgs {
    const void* x; const void* Win; const void* bin; float* h;
    const void* Wq[2]; const void* bq[2];
    const void* Wk[2]; const void* bk[2];
    const void* Wv[2]; const void* bv[2];
    float* wT[2]; float* bp[2];
    const int* ei; int* row_ptr; u16* col_idx;
};
__global__ __launch_bounds__(512) void prep_kernel(PrepArgs a, const int* __restrict__ flagp) {
    __shared__ u32 msk[NNODE * 16];   // 32 KB (only used by last block)
    __shared__ int sc[512];
    int fl = (*flagp != 0);
    int bid = blockIdx.x;
    int tid = threadIdx.x;
    if (bid < 384) {
        // ---- input projection: 8 consecutive h elems per thread
        int base = (bid * 512 + tid) * 8;     // row*64 + j0, j0 multiple of 8
        int row = base >> 6, j0 = base & 63;
        float x0 = ld(a.x, row * 3, fl);
        float x1 = ld(a.x, row * 3 + 1, fl);
        float x2 = ld(a.x, row * 3 + 2, fl);
        float o[8];
#pragma unroll
        for (int jj = 0; jj < 8; ++jj) {
            int j = j0 + jj;
            o[jj] = ld(a.bin, j, fl) + x0 * ld(a.Win, j * 3, fl)
                  + x1 * ld(a.Win, j * 3 + 1, fl) + x2 * ld(a.Win, j * 3 + 2, fl);
        }
        *(float4*)&a.h[base]     = make_float4(o[0], o[1], o[2], o[3]);
        *(float4*)&a.h[base + 4] = make_float4(o[4], o[5], o[6], o[7]);
        return;
    }
    if (bid < 384 + 96) {
        // ---- weight pack: wT[p][l][phase][j][iloc], t = ph*6144 + j*32 + iloc
        int u = (bid - 384) * 512 + tid;  // 0..49151
        int p = u / 24576;
        int rem = u - p * 24576;
        int l = rem / 12288;
        int t = rem - l * 12288;
        int ph   = (t >= 6144) ? 1 : 0;
        int r2   = t - ph * 6144;
        int j    = r2 >> 5;
        int iloc = r2 & 31;
        int i    = ph * 32 + iloc;
        int c = j >> 6, cc = j & 63;
        const void* W = (c == 0) ? a.Wq[p] : (c == 1) ? a.Wk[p] : a.Wv[p];
        a.wT[p][l * 12288 + t] = ld(W, l * 4096 + cc * 64 + i, fl);
        if (ph == 0 && iloc == 0) {
            const void* B = (c == 0) ? a.bq[p] : (c == 1) ? a.bk[p] : a.bv[p];
            a.bp[p][l * 192 + j] = ld(B, l * 64 + cc, fl);
        }
        return;
    }
    // ---- mask bitset (LDS) + CSR build, one 512-thread block
    for (int i = tid; i < NNODE * 16; i += 512) msk[i] = 0;
    __syncthreads();
    for (int e = tid; e < NEDGE; e += 512) {
        int r = a.ei[e];           // query row
        int m = a.ei[NEDGE + e];   // key col
        atomicOr(&msk[r * 16 + (m >> 5)], 1u << (m & 31));
    }
    __syncthreads();
    int n = tid;   // 0..511
    u32 w[16];
    int d = 0;
#pragma unroll
    for (int i = 0; i < 16; ++i) { w[i] = msk[n * 16 + i]; d += __popc(w[i]); }
    sc[n] = d;
    __syncthreads();
    for (int s = 1; s < 512; s <<= 1) {
        int v = (n >= s) ? sc[n - s] : 0;
        __syncthreads();
        sc[n] += v;
        __syncthreads();
    }
    int excl = sc[n] - d;
    a.row_ptr[n] = excl;
    if (n == 511) a.row_ptr[512] = sc[511];
    int base = excl;
#pragma unroll
    for (int i = 0; i < 16; ++i) {
        u32 m = w[i];
        while (m) {
            int b = __ffs(m) - 1;
            m &= m - 1;
            a.col_idx[base++] = (u16)(i * 32 + b);
        }
    }
}

// ---------------- fused q/k/v GEMM v4: h via scalar pipe, W-only LDS ---------
// 256 threads = (wave w = row octet, lane c = col). Both W phases staged once
// (52 KB LDS, 3 blocks/CU). h rows are wave-exclusive and read with a
// readfirstlane-uniform base -> scalar (SMEM) loads, zero LDS traffic for h.
// FMA order over i identical to v3 -> bit-identical outputs.
__global__ __launch_bounds__(256) void qkv_gemm_kernel(
    const float* __restrict__ h, const float* __restrict__ wT,
    const float* __restrict__ bias,
    float* __restrict__ q, float* __restrict__ k, float* __restrict__ v,
    int spatial_layout) {
    __shared__ float wST[2][192][34];  // [phase][col j][iloc], stride 34
    __shared__ float bS[192];
    int t = threadIdx.x;
    int row0 = blockIdx.x * 32;
    // stage both W phases: 12 float4 per thread, linear source
    {
        const float4* src = (const float4*)wT;
#pragma unroll
        for (int kk = 0; kk < 12; ++kk) {
            float4 w4 = src[t + 256 * kk];
            int idx = 4 * (t + 256 * kk);      // 0..12284, mult of 4
            int ph = (idx >= 6144) ? 1 : 0;
            int r2 = idx - ph * 6144;
            int j = r2 >> 5, il = r2 & 31;
            *(float2*)&wST[ph][j][il]     = make_float2(w4.x, w4.y);
            *(float2*)&wST[ph][j][il + 2] = make_float2(w4.z, w4.w);
        }
        if (t < 192) bS[t] = bias[t];
    }
    __syncthreads();
    int c = t & 63, w = t >> 6;
    int rowoff = __builtin_amdgcn_readfirstlane(w * 8);   // uniform row base
    const float* hw = h + (row0 + rowoff) * 64;
    float acc[3][8];
#pragma unroll
    for (int g = 0; g < 3; ++g) {
        float bb = bS[g * 64 + c];
#pragma unroll
        for (int rr = 0; rr < 8; ++rr) acc[g][rr] = bb;
    }
#pragma unroll
    for (int ph = 0; ph < 2; ++ph) {
#pragma unroll 2
        for (int i0 = 0; i0 < 32; i0 += 4) {
            f4 hv[8];
#pragma unroll
            for (int rr = 0; rr < 8; ++rr)
                hv[rr] = *(const f4*)(hw + rr * 64 + ph * 32 + i0);
            f4 wv[3];
#pragma unroll
            for (int g = 0; g < 3; ++g) {
                float2 lo = *(const float2*)&wST[ph][g * 64 + c][i0];
                float2 hi = *(const float2*)&wST[ph][g * 64 + c][i0 + 2];
                wv[g] = (f4){lo.x, lo.y, hi.x, hi.y};
            }
#pragma unroll
            for (int ii = 0; ii < 4; ++ii)
#pragma unroll
                for (int g = 0; g < 3; ++g) {
                    float wf = wv[g][ii];
#pragma unroll
                    for (int rr = 0; rr < 8; ++rr) acc[g][rr] += hv[rr][ii] * wf;
                }
        }
    }
    // ---- epilogue: lane-consecutive stores
    if (spatial_layout) {
        int bs = row0 >> 9, n0 = row0 & 511;
        int hd = c >> 3, dh = c & 7;
        long off = ((long)(bs * 8 + hd) * 512 + n0 + rowoff) * 8 + dh;
        float* qp = q + off;
        float* kp = k + off;
        float* vp = v + off;
#pragma unroll
        for (int rr = 0; rr < 8; ++rr) {
            qp[rr * 8] = acc[0][rr] * QSCALE;
            kp[rr * 8] = acc[1][rr];
            vp[rr * 8] = acc[2][rr];
        }
    } else {
        int off = (row0 + rowoff) * 64 + c;
        float* qp = q + off;
        float* kp = k + off;
        float* vp = v + off;
#pragma unroll
        for (int rr = 0; rr < 8; ++rr) {
            qp[rr * 64] = acc[0][rr];
            kp[rr * 64] = acc[1][rr];
            vp[rr * 64] = acc[2][rr];
        }
    }
}

// ---------------- spatial attention: SPARSE (avg degree 16/512) --------------
__global__ __launch_bounds__(256) void spatial_attn_kernel(
    const float* __restrict__ qh, const float* __restrict__ kh, const float* __restrict__ vh,
    const int* __restrict__ row_ptr, const u16* __restrict__ col_idx,
    float* __restrict__ h) {
    __shared__ __align__(16) float Ks[NNODE][8];   // 16 KB
    __shared__ __align__(16) float Vs[NNODE][8];   // 16 KB
    int bxx = blockIdx.x;
    int pair = bxx >> 1, halfq = bxx & 1;
    int bs = pair >> 3, hd = pair & 7;      // bs = b*S+s in [0,48)
    const float* kp = kh + pair * (NNODE * 8);
    const float* vp = vh + pair * (NNODE * 8);
    int t = threadIdx.x;
#pragma unroll
    for (int i = 0; i < 2; ++i) {
        int r = t + 256 * i;
        float4 k0 = *(const float4*)(kp + r * 8);
        float4 k1 = *(const float4*)(kp + r * 8 + 4);
        float4 v0 = *(const float4*)(vp + r * 8);
        float4 v1 = *(const float4*)(vp + r * 8 + 4);
        *(float4*)&Ks[r][0] = k0; *(float4*)&Ks[r][4] = k1;
        *(float4*)&Vs[r][0] = v0; *(float4*)&Vs[r][4] = v1;
    }
    __syncthreads();
    int n = halfq * 256 + t;
    const float* qp = qh + (pair * NNODE + n) * 8;
    float4 qa = *(const float4*)qp;
    float4 qc = *(const float4*)(qp + 4);
    int e0 = row_ptr[n], e1 = row_ptr[n + 1];
    float l = 0.f;
    float o0=0.f,o1=0.f,o2=0.f,o3=0.f,o4=0.f,o5=0.f,o6=0.f,o7=0.f;
    for (int e = e0; e < e1; ++e) {
        int m = col_idx[e];
        float4 ka = *(const float4*)&Ks[m][0];
        float4 kc = *(const float4*)&Ks[m][4];
        float s = qa.x*ka.x + qa.y*ka.y + qa.z*ka.z + qa.w*ka.w
                + qc.x*kc.x + qc.y*kc.y + qc.z*kc.z + qc.w*kc.w;
        float p = exp2f(s);          // q prescaled by (1/sqrt8)*log2e
        l += p;
        float4 va = *(const float4*)&Vs[m][0];
        float4 vc = *(const float4*)&Vs[m][4];
        o0 += p*va.x; o1 += p*va.y; o2 += p*va.z; o3 += p*va.w;
        o4 += p*vc.x; o5 += p*vc.y; o6 += p*vc.z; o7 += p*vc.w;
    }
    if (e1 == e0) {                  // fully-masked row: uniform mean(V)
        for (int m = 0; m < NNODE; ++m) {
            o0 += Vs[m][0]; o1 += Vs[m][1]; o2 += Vs[m][2]; o3 += Vs[m][3];
            o4 += Vs[m][4]; o5 += Vs[m][5]; o6 += Vs[m][6]; o7 += Vs[m][7];
        }
        l = (float)NNODE;
    }
    float inv = 1.f / l;
    float* op = h + (bs * NNODE + n) * HIDN + hd * 8;
    *(float4*)op       = make_float4(o0*inv, o1*inv, o2*inv, o3*inv);
    *(float4*)(op + 4) = make_float4(o4*inv, o5*inv, o6*inv, o7*inv);
}

// ---------------- temporal attention v2: LDS-staged K/V ----------------------
__global__ __launch_bounds__(768) void temporal_attn_kernel(
    const float* __restrict__ q, const float* __restrict__ k, const float* __restrict__ v,
    float* __restrict__ h) {
    __shared__ float Ks2[SS][8][68];   // 26 KB
    __shared__ float Vs2[SS][8][68];   // 26 KB
    int b  = blockIdx.x >> 6;
    int n0 = (blockIdx.x & 63) * 8;
    int t = threadIdx.x;
#pragma unroll
    for (int j = 0; j < 2; ++j) {
        int fid = t + 768 * j;            // 0..1535
        int tt  = fid >> 7;
        int rem = fid & 127;
        int nl  = rem >> 4;
        int dq  = rem & 15;
        long goff = ((long)((b * SS + tt) * NNODE) + n0 + nl) * HIDN + dq * 4;
        *(float4*)&Ks2[tt][nl][dq * 4] = *(const float4*)(k + goff);
        *(float4*)&Vs2[tt][nl][dq * 4] = *(const float4*)(v + goff);
    }
    __syncthreads();
    int hd = t & 7, nl = (t >> 3) & 7, sq = t >> 6;   // sq 0..11
    const float* qp = q + ((long)((b * SS + sq) * NNODE) + n0 + nl) * HIDN + hd * 8;
    float4 qa = *(const float4*)qp;
    float4 qc = *(const float4*)(qp + 4);
    float s[SS];
#pragma unroll
    for (int tt = 0; tt < SS; ++tt) {
        float4 ka = *(const float4*)&Ks2[tt][nl][hd * 8];
        float4 kc = *(const float4*)&Ks2[tt][nl][hd * 8 + 4];
        s[tt] = (qa.x * ka.x + qa.y * ka.y + qa.z * ka.z + qa.w * ka.w +
                 qc.x * kc.x + qc.y * kc.y + qc.z * kc.z + qc.w * kc.w) * QSCALE;
    }
    float mx = s[0];
#pragma unroll
    for (int tt = 1; tt < SS; ++tt) mx = fmaxf(mx, s[tt]);
    float l = 0.f;
#pragma unroll
    for (int tt = 0; tt < SS; ++tt) { s[tt] = exp2f(s[tt] - mx); l += s[tt]; }
    float a0 = 0.f, a1 = 0.f, a2 = 0.f, a3 = 0.f, a4 = 0.f, a5 = 0.f, a6 = 0.f, a7 = 0.f;
#pragma unroll
    for (int tt = 0; tt < SS; ++tt) {
        float4 va = *(const float4*)&Vs2[tt][nl][hd * 8];
        float4 vc = *(const float4*)&Vs2[tt][nl][hd * 8 + 4];
        float e = s[tt];
        a0 += e * va.x; a1 += e * va.y; a2 += e * va.z; a3 += e * va.w;
        a4 += e * vc.x; a5 += e * vc.y; a6 += e * vc.z; a7 += e * vc.w;
    }
    float inv = 1.f / l;
    float* op = h + ((long)((b * SS + sq) * NNODE) + n0 + nl) * HIDN + hd * 8;
    *(float4*)op       = make_float4(a0 * inv, a1 * inv, a2 * inv, a3 * inv);
    *(float4*)(op + 4) = make_float4(a4 * inv, a5 * inv, a6 * inv, a7 * inv);
}

// ---------------- output projection: h[:, S-1] @ raw WoutT + raw bout --------
__global__ void out_proj_kernel(const float* __restrict__ h, const void* __restrict__ W,
                                const void* __restrict__ b, void* __restrict__ out,
                                const int* __restrict__ flagp) {
    int fl = (*flagp != 0);
    int t = blockIdx.x * blockDim.x + threadIdx.x;
    if (t >= BB * NNODE * 3) return;
    int c  = t % 3;
    int bn = t / 3;
    int n  = bn & (NNODE - 1);
    int bb = bn >> 9;
    const float* hp = h + ((bb * SS + (SS - 1)) * NNODE + n) * HIDN;
    float a = ld(b, c, fl);
#pragma unroll
    for (int i = 0; i < HIDN; i += 4) {
        float4 h4 = *(const float4*)(hp + i);
        a += h4.x * ld(W, c * 64 + i,     fl) + h4.y * ld(W, c * 64 + i + 1, fl)
           + h4.z * ld(W, c * 64 + i + 2, fl) + h4.w * ld(W, c * 64 + i + 3, fl);
    }
    if (fl) ((float*)out)[t] = a;
    else    ((__hip_bfloat16*)out)[t] = __float2bfloat16(a);
}

extern "C" void kernel_launch(void* const* d_in, const int* in_sizes, int n_in,
                              void* d_out, int out_size, void* d_ws, size_t ws_size,
                              hipStream_t stream) {
    const int* ei = (const int*)d_in[1];

    float* ws = (float*)d_ws;
    int*   flag    = (int*)ws;                    // 64 floats reserved
    int*   row_ptr = (int*)(ws + 64);             // 513 ints (reserve 576)
    u16*   col_idx = (u16*)(ws + 640);            // 8192 u16 (4096 float slots)
    float* wTs   = ws + 640 + 4096;               // 2*12288
    float* wTt   = wTs + 24576;                   // 2*12288
    float* bsp   = wTt + 24576;                   // 2*192
    float* btp   = bsp + 384;                     // 2*192
    float* hbuf  = btp + 384;                     // ROWS*64 each
    float* qbuf  = hbuf + ROWS * HIDN;
    float* kbuf  = qbuf + ROWS * HIDN;
    float* vbuf  = kbuf + ROWS * HIDN;

    // dtype from host-visible byte sizes; runtime-detect only if ambiguous
    int flv = -1;
    if (in_sizes) {
        if (in_sizes[0] == XELEMS * 2) flv = 0;        // bf16
        else if (in_sizes[0] == XELEMS * 4) flv = 1;   // fp32
    }
    if (flv >= 0) {
        (void)hipMemsetAsync(flag, flv, sizeof(int), stream);
    } else {
        (void)hipMemsetAsync(flag, 0, sizeof(int), stream);
        detect_kernel<<<64, 256, 0, stream>>>((const u16*)d_in[0], flag);
    }

    PrepArgs pr;
    pr.x = d_in[0]; pr.Win = d_in[2]; pr.bin = d_in[3]; pr.h = hbuf;
    pr.Wq[0] = d_in[4];  pr.bq[0] = d_in[5];
    pr.Wk[0] = d_in[6];  pr.bk[0] = d_in[7];
    pr.Wv[0] = d_in[8];  pr.bv[0] = d_in[9];
    pr.Wq[1] = d_in[10]; pr.bq[1] = d_in[11];
    pr.Wk[1] = d_in[12]; pr.bk[1] = d_in[13];
    pr.Wv[1] = d_in[14]; pr.bv[1] = d_in[15];
    pr.wT[0] = wTs; pr.bp[0] = bsp;
    pr.wT[1] = wTt; pr.bp[1] = btp;
    pr.ei = ei; pr.row_ptr = row_ptr; pr.col_idx = col_idx;
    prep_kernel<<<384 + 96 + 1, 512, 0, stream>>>(pr, flag);

    const int GEMM_BLOCKS = ROWS / 32;                       // 768
    for (int l = 0; l < NLAY; ++l) {
        // spatial
        qkv_gemm_kernel<<<GEMM_BLOCKS, 256, 0, stream>>>(
            hbuf, wTs + l * 12288, bsp + l * 192, qbuf, kbuf, vbuf, 1);
        spatial_attn_kernel<<<BB * SS * NHEADS * 2, 256, 0, stream>>>(
            qbuf, kbuf, vbuf, row_ptr, col_idx, hbuf);
        // temporal
        qkv_gemm_kernel<<<GEMM_BLOCKS, 256, 0, stream>>>(
            hbuf, wTt + l * 12288, btp + l * 192, qbuf, kbuf, vbuf, 0);
        temporal_attn_kernel<<<BB * (NNODE / 8), 768, 0, stream>>>(
            qbuf, kbuf, vbuf, hbuf);
    }
    out_proj_kernel<<<(BB * NNODE * 3 + 255) / 256, 256, 0, stream>>>(
        hbuf, d_in[16], d_in[17], d_out, flag);
}